// Round 4
// baseline (1108.352 us; speedup 1.0000x reference)
//
#include <hip/hip_runtime.h>
#include <hip/hip_bf16.h>
#include <stdint.h>

// ---------- types ----------
typedef __bf16  bf16x8  __attribute__((ext_vector_type(8)));
typedef float   f32x4   __attribute__((ext_vector_type(4)));
typedef unsigned short u16x8 __attribute__((ext_vector_type(8)));
typedef unsigned short u16x4 __attribute__((ext_vector_type(4)));
typedef unsigned short ushort_t;

__device__ __forceinline__ unsigned short f2b(float f) {
    __hip_bfloat16 h = __float2bfloat16(f);   // RNE
    return *reinterpret_cast<unsigned short*>(&h);
}

// async 16B global->LDS (direct-to-LDS DMA; LDS dest is wave-uniform base + lane*16)
__device__ __forceinline__ void cp16(const void* g, void* l) {
    __builtin_amdgcn_global_load_lds(
        (const __attribute__((address_space(1))) unsigned int*)g,
        (__attribute__((address_space(3))) unsigned int*)l,
        16, 0, 0);
}

// dims
#define BB 8
#define LL 2048
#define DM 64
#define NH 4
#define DK 64

// ---------- K0: pack mask int32 -> bits (k-major, 32 keys/word) ----------
__global__ __launch_bounds__(256) void k_maskpack(const int* __restrict__ mask,
                                                  unsigned int* __restrict__ words) {
    int tid = blockIdx.x * 256 + threadIdx.x;        // word index, 1,048,576 total
    const int4* p = reinterpret_cast<const int4*>(mask) + (size_t)tid * 8;
    unsigned int wbits = 0u;
    #pragma unroll
    for (int i = 0; i < 8; i++) {
        int4 v = p[i];
        wbits |= (v.x != 0 ? 1u << (4 * i + 0) : 0u);
        wbits |= (v.y != 0 ? 1u << (4 * i + 1) : 0u);
        wbits |= (v.z != 0 ? 1u << (4 * i + 2) : 0u);
        wbits |= (v.w != 0 ? 1u << (4 * i + 3) : 0u);
    }
    words[tid] = wbits;
}

// ---------- K1: gates S_q,S_k,S_v per batch ----------
__global__ __launch_bounds__(64) void k_gates(const float* __restrict__ u,
                                              const float* s1q, const float* s2q,
                                              const float* s1k, const float* s2k,
                                              const float* s1v, const float* s2v,
                                              float* __restrict__ gates) {
    int b = blockIdx.x, g = blockIdx.y, lane = threadIdx.x;
    const float* s1 = (g == 0) ? s1q : (g == 1) ? s1k : s1v;
    const float* s2 = (g == 0) ? s2q : (g == 1) ? s2k : s2v;
    float ur = u[b * 64 + lane];
    float acc = 0.f;
    for (int j = 0; j < 64; j++) {
        float uj = __shfl(ur, j, 64);
        if (lane < 32) acc += uj * s1[j * 32 + lane];
    }
    float r = (lane < 32) ? fmaxf(acc, 0.f) * s2[lane] : 0.f;
    for (int m = 32; m >= 1; m >>= 1) r += __shfl_xor(r, m, 64);
    if (lane == 0) gates[b * 3 + g] = r;
}

// ---------- K2: projections ----------
// Qe [b,h,L,128] linear (scaled 1/8).
// Ke [b,h,L,128] with col XOR-swizzle: element (l,c) stored at c ^ ((l&7)<<3).
// VeT [b,h,64,L] = (V+uV)^T with per-64-block col swizzle: within each 64-col block,
//   element (d,l) stored at (l&63) ^ ((d&7)<<3).
__global__ __launch_bounds__(256) void k_proj(const float* __restrict__ x,
                                              const float* __restrict__ wq,
                                              const float* __restrict__ wk,
                                              const float* __restrict__ wv,
                                              const float* __restrict__ uqw,
                                              const float* __restrict__ ukw,
                                              const float* __restrict__ uvw,
                                              const float* __restrict__ gates,
                                              ushort_t* __restrict__ Qe,
                                              ushort_t* __restrict__ Ke,
                                              ushort_t* __restrict__ VeT) {
    int lt = blockIdx.x, b = blockIdx.y, t = threadIdx.x;
    int l0 = lt * 32;
    __shared__ float lx[32][68];
    __shared__ float luv[32][68];
    #pragma unroll
    for (int i = 0; i < 2; i++) {      // stage x tile: 32x64 floats
        int id = t + i * 256;
        int r = id >> 4, c4 = id & 15;
        float4 v = *(const float4*)&x[((b * LL) + l0 + r) * 64 + c4 * 4];
        *(float4*)&lx[r][c4 * 4] = v;
    }
    __syncthreads();
    float Sq = gates[b * 3 + 0], Sk = gates[b * 3 + 1], Sv = gates[b * 3 + 2];
    // u-projections (waves 0..2)
    if (t < 192) {
        int m = t >> 6, d = t & 63;
        const float* uw = (m == 0) ? uqw : (m == 1) ? ukw : uvw;
        float acc[32];
        #pragma unroll
        for (int r = 0; r < 32; r++) acc[r] = 0.f;
        for (int j = 0; j < 64; j += 4) {
            float w0 = uw[(j + 0) * 64 + d], w1 = uw[(j + 1) * 64 + d];
            float w2 = uw[(j + 2) * 64 + d], w3 = uw[(j + 3) * 64 + d];
            #pragma unroll
            for (int r = 0; r < 32; r++) {
                float4 xv = *(const float4*)&lx[r][j];
                acc[r] += xv.x * w0 + xv.y * w1 + xv.z * w2 + xv.w * w3;
            }
        }
        if (m == 2) {
            #pragma unroll
            for (int r = 0; r < 32; r++) luv[r][d] = acc[r] * Sv;
        } else if (m == 0) {
            for (int r = 0; r < 32; r++) {
                unsigned short v = f2b(acc[r] * Sq * 0.125f);
                int base = ((b * NH) * LL + l0 + r) * 128 + 64 + d;
                #pragma unroll
                for (int hh2 = 0; hh2 < 4; hh2++) Qe[base + hh2 * (LL * 128)] = v;
            }
        } else {
            for (int r = 0; r < 32; r++) {
                unsigned short v = f2b(acc[r] * Sk);
                int col = 64 + (d ^ ((r & 7) << 3));   // Ke swizzle (row&7 == r&7)
                int base = ((b * NH) * LL + l0 + r) * 128 + col;
                #pragma unroll
                for (int hh2 = 0; hh2 < 4; hh2++) Ke[base + hh2 * (LL * 128)] = v;
            }
        }
    }
    __syncthreads();
    // fused head projections: thread = output column c (q,k,v simultaneously)
    int c = t, hh = c >> 6, d = c & 63;
    float aq_[32], ak_[32], av_[32];
    #pragma unroll
    for (int r = 0; r < 32; r++) { aq_[r] = 0.f; ak_[r] = 0.f; av_[r] = 0.f; }
    for (int j = 0; j < 64; j += 4) {
        float q0w = wq[(j + 0) * 256 + c], q1w = wq[(j + 1) * 256 + c];
        float q2w = wq[(j + 2) * 256 + c], q3w = wq[(j + 3) * 256 + c];
        float k0w = wk[(j + 0) * 256 + c], k1w = wk[(j + 1) * 256 + c];
        float k2w = wk[(j + 2) * 256 + c], k3w = wk[(j + 3) * 256 + c];
        float v0w = wv[(j + 0) * 256 + c], v1w = wv[(j + 1) * 256 + c];
        float v2w = wv[(j + 2) * 256 + c], v3w = wv[(j + 3) * 256 + c];
        #pragma unroll
        for (int r = 0; r < 32; r++) {
            float4 xv = *(const float4*)&lx[r][j];
            aq_[r] += xv.x * q0w + xv.y * q1w + xv.z * q2w + xv.w * q3w;
            ak_[r] += xv.x * k0w + xv.y * k1w + xv.z * k2w + xv.w * k3w;
            av_[r] += xv.x * v0w + xv.y * v1w + xv.z * v2w + xv.w * v3w;
        }
    }
    int outbase = (b * NH + hh) * LL + l0;
    #pragma unroll
    for (int r = 0; r < 32; r++) Qe[(outbase + r) * 128 + d] = f2b(aq_[r] * 0.125f);
    #pragma unroll
    for (int r = 0; r < 32; r++)
        Ke[(outbase + r) * 128 + (d ^ ((r & 7) << 3))] = f2b(ak_[r]);
    // VeT with swizzle: 8-element blocks permuted inside each 64-col block
    long vbase = ((long)(b * NH + hh) * 64 + d) * LL;
    int lblk = l0 & ~63, loff = l0 & 63;
    #pragma unroll
    for (int rb = 0; rb < 4; rb++) {
        u16x8 vv;
        #pragma unroll
        for (int k = 0; k < 8; k++) {
            int r = rb * 8 + k;
            vv[k] = f2b(av_[r] + luv[r][d]);
        }
        int off = (loff + rb * 8) ^ ((d & 7) << 3);
        *(u16x8*)&VeT[vbase + lblk + off] = vv;
    }
}

// ---------- K3: attention core (two-pass, swapped-QK layout, async dbuf LDS) ----------
// grid (32 qtiles, 4 heads, 8 batches), 256 threads = 4 waves; wave w owns q-rows
// w*16..w*16+15. QK MFMA computed SWAPPED (mfma(kb, aq)) so each lane holds 4
// consecutive k-cols of one q-row (q=l15): attn stores become float4 (full-line
// L2 write-combining), sPb writes become b64, mask reads halve.
__global__ __launch_bounds__(256) void k_attn(const ushort_t* __restrict__ Qe,
                                              const ushort_t* __restrict__ Ke,
                                              const ushort_t* __restrict__ VeT,
                                              const unsigned int* __restrict__ mwords,
                                              float* __restrict__ ctx,
                                              float* __restrict__ attn) {
    // bijective XCD swizzle over 1024 blocks: lin%8 (XCD) picks the batch
    int lin = blockIdx.x + 32 * blockIdx.y + 128 * blockIdx.z;
    int sw  = ((lin & 7) << 7) | (lin >> 3);
    int qt = sw & 31, h = (sw >> 5) & 3, b = sw >> 7;

    int t = threadIdx.x, w = t >> 6, lane = t & 63, quad = lane >> 4, l15 = lane & 15;
    int q0 = qt * 64;
    int bh = b * NH + h;
    const ushort_t* QeB = Qe + (long)bh * LL * 128;
    const ushort_t* KeB = Ke + (long)bh * LL * 128;
    const ushort_t* VtB = VeT + (long)bh * 64 * LL;
    float* attnB = attn + (long)bh * LL * LL;
    const unsigned int* mB = mwords + (long)(b * LL) * 64;

    __shared__ ushort_t sKe[2][64 * 128];     // 32 KB dbuf (linear, swizzled content)
    __shared__ ushort_t sVT[2][64 * 64];      // 16 KB dbuf
    __shared__ unsigned int smask[64][66];    // 16.9 KB
    __shared__ ushort_t sPb[4][16][72];       //  9.2 KB per-wave unnormalized P (bf16)

    // stage this q-tile's mask bits (64 rows x 64 words) -- once
    #pragma unroll
    for (int i = 0; i < 16; i++) {
        int id = t + i * 256;
        smask[id >> 6][id & 63] = mB[(q0 + (id >> 6)) * 64 + (id & 63)];
    }

    // Q fragments for this wave's 16 rows (Qe linear); lane l15 = q-row
    bf16x8 aq[4];
    int qrow = q0 + w * 16 + l15;
    #pragma unroll
    for (int c = 0; c < 4; c++)
        aq[c] = *(const bf16x8*)&QeB[qrow * 128 + c * 32 + quad * 8];

    int swz = (l15 & 7) << 3;                  // element XOR for swizzled LDS reads
    float lsum = 0.f;                          // partial row sum for q-row l15

    // ---- pass A: row sums ----
    #pragma unroll
    for (int i = 0; i < 4; i++) {              // prologue: Ke tile 0 -> buf0
        int off = (t + i * 256) * 16;
        cp16((const char*)KeB + off, (char*)&sKe[0][0] + off);
    }
    for (int kt = 0; kt < 32; kt++) {
        int cur = kt & 1;
        __syncthreads();                       // tile kt resident; smask visible (kt=0)
        if (kt < 31) {
            size_t gb = (size_t)(kt + 1) * 64 * 256;
            #pragma unroll
            for (int i = 0; i < 4; i++) {
                int off = (t + i * 256) * 16;
                cp16((const char*)KeB + gb + off, (char*)&sKe[cur ^ 1][0] + off);
            }
        }
        #pragma unroll
        for (int nb = 0; nb < 4; nb++) {
            f32x4 s = (f32x4){0.f, 0.f, 0.f, 0.f};
            #pragma unroll
            for (int c = 0; c < 4; c++) {
                bf16x8 kb = *(const bf16x8*)&sKe[cur][(nb * 16 + l15) * 128 + ((c * 32 + quad * 8) ^ swz)];
                s = __builtin_amdgcn_mfma_f32_16x16x32_bf16(kb, aq[c], s, 0, 0, 0);
            }
            unsigned int word = smask[w * 16 + l15][kt * 2 + (nb >> 1)];
            #pragma unroll
            for (int reg = 0; reg < 4; reg++) {
                unsigned int bit = (word >> ((nb & 1) * 16 + quad * 4 + reg)) & 1u;
                lsum += bit ? 0.f : __expf(fminf(s[reg], 60.f));
            }
        }
    }
    // full row sum for q-row l15: reduce across the 4 quads
    {
        lsum += __shfl_xor(lsum, 16, 64);
        lsum += __shfl_xor(lsum, 32, 64);
    }
    float inv = (lsum > 0.f) ? 1.f / lsum : 0.f;   // inverse for row l15
    float invC[4];                                 // inverse for row quad*4+reg (ctx)
    #pragma unroll
    for (int reg = 0; reg < 4; reg++) invC[reg] = __shfl(inv, quad * 4 + reg, 16);

    // ---- pass B: normalized attn store + PV ----
    f32x4 cacc[4];
    #pragma unroll
    for (int db = 0; db < 4; db++) cacc[db] = (f32x4){0.f, 0.f, 0.f, 0.f};

    // prologue: tile 0 of Ke + VeT (buf0 free: all waves past pass-A kt=31 barrier)
    #pragma unroll
    for (int i = 0; i < 4; i++) {
        int off = (t + i * 256) * 16;
        cp16((const char*)KeB + off, (char*)&sKe[0][0] + off);
    }
    #pragma unroll
    for (int i = 0; i < 2; i++) {
        int off = (t + i * 256) * 16;          // LDS byte offset in 8 KB tile
        int d = off >> 7, cb = off & 127;      // row d (0..63), col byte
        cp16((const char*)VtB + (size_t)d * (LL * 2) + cb, (char*)&sVT[0][0] + off);
    }
    for (int kt = 0; kt < 32; kt++) {
        int cur = kt & 1;
        int k0 = kt * 64;
        __syncthreads();
        if (kt < 31) {
            size_t gKe = (size_t)(k0 + 64) * 256;
            #pragma unroll
            for (int i = 0; i < 4; i++) {
                int off = (t + i * 256) * 16;
                cp16((const char*)KeB + gKe + off, (char*)&sKe[cur ^ 1][0] + off);
            }
            #pragma unroll
            for (int i = 0; i < 2; i++) {
                int off = (t + i * 256) * 16;
                int d = off >> 7, cb = off & 127;
                cp16((const char*)VtB + (size_t)d * (LL * 2) + (size_t)(k0 + 64) * 2 + cb,
                     (char*)&sVT[cur ^ 1][0] + off);
            }
        }
        #pragma unroll
        for (int nb = 0; nb < 4; nb++) {
            f32x4 s = (f32x4){0.f, 0.f, 0.f, 0.f};
            #pragma unroll
            for (int c = 0; c < 4; c++) {
                bf16x8 kb = *(const bf16x8*)&sKe[cur][(nb * 16 + l15) * 128 + ((c * 32 + quad * 8) ^ swz)];
                s = __builtin_amdgcn_mfma_f32_16x16x32_bf16(kb, aq[c], s, 0, 0, 0);
            }
            unsigned int word = smask[w * 16 + l15][kt * 2 + (nb >> 1)];
            u16x4 pk;
            float4 st;
            #pragma unroll
            for (int reg = 0; reg < 4; reg++) {
                unsigned int bit = (word >> ((nb & 1) * 16 + quad * 4 + reg)) & 1u;
                float p = bit ? 0.f : __expf(fminf(s[reg], 60.f));
                pk[reg] = f2b(p);
                ((float*)&st)[reg] = p * inv;
            }
            *(u16x4*)&sPb[w][l15][nb * 16 + quad * 4] = pk;
            // normal (cached) store: the two 64B halves of each 128B line come from
            // consecutive nb -> L2 write-combines into full-line HBM writebacks
            *(float4*)&attnB[(long)(q0 + w * 16 + l15) * LL + k0 + nb * 16 + quad * 4] = st;
        }
        // ctx += P @ Ve (unnormalized P; normalized at the end)
        #pragma unroll
        for (int db = 0; db < 4; db++) {
            #pragma unroll
            for (int c2 = 0; c2 < 2; c2++) {
                bf16x8 a  = *(const bf16x8*)&sPb[w][l15][c2 * 32 + quad * 8];
                bf16x8 bb = *(const bf16x8*)&sVT[cur][(db * 16 + l15) * 64 + ((c2 * 32 + quad * 8) ^ swz)];
                cacc[db] = __builtin_amdgcn_mfma_f32_16x16x32_bf16(a, bb, cacc[db], 0, 0, 0);
            }
        }
    }
    // normalized ctx -> ws [b,L,256] fp32 (cacc row = quad*4+reg -> invC)
    #pragma unroll
    for (int db = 0; db < 4; db++)
        #pragma unroll
        for (int reg = 0; reg < 4; reg++) {
            int qr = q0 + w * 16 + quad * 4 + reg;
            ctx[((long)(b * LL) + qr) * 256 + h * 64 + db * 16 + l15] = cacc[db][reg] * invC[reg];
        }
}

// ---------- K5: fc + residual + LN1 + FFN + LN2 ----------
__global__ __launch_bounds__(256) void k_epi(const float* __restrict__ ctx,
                                             const float* __restrict__ x,
                                             const float* __restrict__ fcw,
                                             const float* __restrict__ g1,
                                             const float* __restrict__ b1,
                                             const float* __restrict__ f1,
                                             const float* __restrict__ f2,
                                             const float* __restrict__ g2,
                                             const float* __restrict__ b2w,
                                             float* __restrict__ res) {
    int w = threadIdx.x >> 6, lane = threadIdx.x & 63;
    int row = blockIdx.x * 4 + w;
    const float* cr = ctx + (long)row * 256;
    float creg[4];
    #pragma unroll
    for (int i = 0; i < 4; i++) creg[i] = cr[i * 64 + lane];
    float acc = 0.f;
    #pragma unroll
    for (int j = 0; j < 256; j++) {
        float cj = __shfl(creg[j >> 6], j & 63, 64);
        acc += cj * fcw[j * 64 + lane];
    }
    float val = acc + x[row * 64 + lane];
    float mu = val;
    #pragma unroll
    for (int m = 1; m < 64; m <<= 1) mu += __shfl_xor(mu, m, 64);
    mu *= (1.f / 64.f);
    float d0 = val - mu;
    float var = d0 * d0;
    #pragma unroll
    for (int m = 1; m < 64; m <<= 1) var += __shfl_xor(var, m, 64);
    var *= (1.f / 64.f);
    float enc = d0 * rsqrtf(var + 1e-5f) * g1[lane] + b1[lane];
    float a1 = 0.f;
    #pragma unroll
    for (int j = 0; j < 64; j++) a1 += __shfl(enc, j, 64) * f1[j * 64 + lane];
    float hrel = fmaxf(a1, 0.f);
    float a2 = 0.f;
    #pragma unroll
    for (int j = 0; j < 64; j++) a2 += __shfl(hrel, j, 64) * f2[j * 64 + lane];
    float v2 = a2 + enc;
    float mu2 = v2;
    #pragma unroll
    for (int m = 1; m < 64; m <<= 1) mu2 += __shfl_xor(mu2, m, 64);
    mu2 *= (1.f / 64.f);
    float d2 = v2 - mu2;
    float var2 = d2 * d2;
    #pragma unroll
    for (int m = 1; m < 64; m <<= 1) var2 += __shfl_xor(var2, m, 64);
    var2 *= (1.f / 64.f);
    float outv = d2 * rsqrtf(var2 + 1e-5f) * g2[lane] + b2w[lane];
    res[row * 64 + lane] = outv;
}

// ---------- launch ----------
extern "C" void kernel_launch(void* const* d_in, const int* in_sizes, int n_in,
                              void* d_out, int out_size, void* d_ws, size_t ws_size,
                              hipStream_t stream) {
    const float* x    = (const float*)d_in[0];
    const int*   mask = (const int*)d_in[1];
    const float* u    = (const float*)d_in[2];
    const float* wq   = (const float*)d_in[3];
    const float* wk   = (const float*)d_in[4];
    const float* wv   = (const float*)d_in[5];
    const float* uqw  = (const float*)d_in[6];
    const float* ukw  = (const float*)d_in[7];
    const float* uvw  = (const float*)d_in[8];
    const float* sq1  = (const float*)d_in[9];
    const float* sq2  = (const float*)d_in[10];
    const float* sk1  = (const float*)d_in[11];
    const float* sk2  = (const float*)d_in[12];
    const float* sv1  = (const float*)d_in[13];
    const float* sv2  = (const float*)d_in[14];
    const float* fcw  = (const float*)d_in[15];
    const float* g1   = (const float*)d_in[16];
    const float* b1   = (const float*)d_in[17];
    const float* f1   = (const float*)d_in[18];
    const float* f2   = (const float*)d_in[19];
    const float* g2   = (const float*)d_in[20];
    const float* b2w  = (const float*)d_in[21];

    char* ws = (char*)d_ws;
    float*        gates  = (float*)(ws + 0);
    unsigned int* mwords = (unsigned int*)(ws + 4096);              // 4,194,304 B
    ushort_t*     Qe     = (ushort_t*)(ws + 4198400);               // 16,777,216 B
    ushort_t*     Ke     = (ushort_t*)(ws + 20975616);              // 16,777,216 B
    ushort_t*     VeT    = (ushort_t*)(ws + 37752832);              //  8,388,608 B
    float*        ctx    = (float*)(ws + 46141440);                 // 16,777,216 B (end ~63 MB)

    float* res  = (float*)d_out;
    float* attn = (float*)d_out + (size_t)BB * LL * DM;             // offset 1,048,576 elems

    k_maskpack<<<dim3(4096), dim3(256), 0, stream>>>(mask, mwords);
    k_gates<<<dim3(8, 3), dim3(64), 0, stream>>>(u, sq1, sq2, sk1, sk2, sv1, sv2, gates);
    k_proj<<<dim3(64, 8), dim3(256), 0, stream>>>(x, wq, wk, wv, uqw, ukw, uvw, gates, Qe, Ke, VeT);
    k_attn<<<dim3(32, 4, 8), dim3(256), 0, stream>>>(Qe, Ke, VeT, mwords, ctx, attn);
    k_epi<<<dim3(4096), dim3(256), 0, stream>>>(ctx, x, fcw, g1, b1, f1, f2, g2, b2w, res);
}

// Round 5
// 1019.387 us; speedup vs baseline: 1.0873x; 1.0873x over previous
//
#include <hip/hip_runtime.h>
#include <hip/hip_bf16.h>
#include <stdint.h>

// ---------- types ----------
typedef __bf16  bf16x8  __attribute__((ext_vector_type(8)));
typedef float   f32x4   __attribute__((ext_vector_type(4)));
typedef unsigned short u16x8 __attribute__((ext_vector_type(8)));
typedef unsigned short u16x4 __attribute__((ext_vector_type(4)));
typedef unsigned short ushort_t;

__device__ __forceinline__ unsigned short f2b(float f) {
    __hip_bfloat16 h = __float2bfloat16(f);   // RNE
    return *reinterpret_cast<unsigned short*>(&h);
}

// async 16B global->LDS (direct-to-LDS DMA; LDS dest is wave-uniform base + lane*16)
__device__ __forceinline__ void cp16(const void* g, void* l) {
    __builtin_amdgcn_global_load_lds(
        (const __attribute__((address_space(1))) unsigned int*)g,
        (__attribute__((address_space(3))) unsigned int*)l,
        16, 0, 0);
}

// dims
#define BB 8
#define LL 2048
#define DM 64
#define NH 4
#define DK 64

// ---------- K0: pack mask int32 -> bits (k-major, 32 keys/word) ----------
__global__ __launch_bounds__(256) void k_maskpack(const int* __restrict__ mask,
                                                  unsigned int* __restrict__ words) {
    int tid = blockIdx.x * 256 + threadIdx.x;        // word index, 1,048,576 total
    const int4* p = reinterpret_cast<const int4*>(mask) + (size_t)tid * 8;
    unsigned int wbits = 0u;
    #pragma unroll
    for (int i = 0; i < 8; i++) {
        int4 v = p[i];
        wbits |= (v.x != 0 ? 1u << (4 * i + 0) : 0u);
        wbits |= (v.y != 0 ? 1u << (4 * i + 1) : 0u);
        wbits |= (v.z != 0 ? 1u << (4 * i + 2) : 0u);
        wbits |= (v.w != 0 ? 1u << (4 * i + 3) : 0u);
    }
    words[tid] = wbits;
}

// ---------- K1: gates S_q,S_k,S_v per batch ----------
__global__ __launch_bounds__(64) void k_gates(const float* __restrict__ u,
                                              const float* s1q, const float* s2q,
                                              const float* s1k, const float* s2k,
                                              const float* s1v, const float* s2v,
                                              float* __restrict__ gates) {
    int b = blockIdx.x, g = blockIdx.y, lane = threadIdx.x;
    const float* s1 = (g == 0) ? s1q : (g == 1) ? s1k : s1v;
    const float* s2 = (g == 0) ? s2q : (g == 1) ? s2k : s2v;
    float ur = u[b * 64 + lane];
    float acc = 0.f;
    for (int j = 0; j < 64; j++) {
        float uj = __shfl(ur, j, 64);
        if (lane < 32) acc += uj * s1[j * 32 + lane];
    }
    float r = (lane < 32) ? fmaxf(acc, 0.f) * s2[lane] : 0.f;
    for (int m = 32; m >= 1; m >>= 1) r += __shfl_xor(r, m, 64);
    if (lane == 0) gates[b * 3 + g] = r;
}

// ---------- K2: projections ----------
// Qe [b,h,L,128] linear (scaled 1/8).
// Ke [b,h,L,128] with col XOR-swizzle: element (l,c) stored at c ^ ((l&7)<<3).
// VeT [b,h,64,L] = (V+uV)^T with per-64-block col swizzle: within each 64-col block,
//   element (d,l) stored at (l&63) ^ ((d&7)<<3).
__global__ __launch_bounds__(256) void k_proj(const float* __restrict__ x,
                                              const float* __restrict__ wq,
                                              const float* __restrict__ wk,
                                              const float* __restrict__ wv,
                                              const float* __restrict__ uqw,
                                              const float* __restrict__ ukw,
                                              const float* __restrict__ uvw,
                                              const float* __restrict__ gates,
                                              ushort_t* __restrict__ Qe,
                                              ushort_t* __restrict__ Ke,
                                              ushort_t* __restrict__ VeT) {
    int lt = blockIdx.x, b = blockIdx.y, t = threadIdx.x;
    int l0 = lt * 32;
    __shared__ float lx[32][68];
    __shared__ float luv[32][68];
    #pragma unroll
    for (int i = 0; i < 2; i++) {      // stage x tile: 32x64 floats
        int id = t + i * 256;
        int r = id >> 4, c4 = id & 15;
        float4 v = *(const float4*)&x[((b * LL) + l0 + r) * 64 + c4 * 4];
        *(float4*)&lx[r][c4 * 4] = v;
    }
    __syncthreads();
    float Sq = gates[b * 3 + 0], Sk = gates[b * 3 + 1], Sv = gates[b * 3 + 2];
    // u-projections (waves 0..2)
    if (t < 192) {
        int m = t >> 6, d = t & 63;
        const float* uw = (m == 0) ? uqw : (m == 1) ? ukw : uvw;
        float acc[32];
        #pragma unroll
        for (int r = 0; r < 32; r++) acc[r] = 0.f;
        for (int j = 0; j < 64; j += 4) {
            float w0 = uw[(j + 0) * 64 + d], w1 = uw[(j + 1) * 64 + d];
            float w2 = uw[(j + 2) * 64 + d], w3 = uw[(j + 3) * 64 + d];
            #pragma unroll
            for (int r = 0; r < 32; r++) {
                float4 xv = *(const float4*)&lx[r][j];
                acc[r] += xv.x * w0 + xv.y * w1 + xv.z * w2 + xv.w * w3;
            }
        }
        if (m == 2) {
            #pragma unroll
            for (int r = 0; r < 32; r++) luv[r][d] = acc[r] * Sv;
        } else if (m == 0) {
            for (int r = 0; r < 32; r++) {
                unsigned short v = f2b(acc[r] * Sq * 0.125f);
                int base = ((b * NH) * LL + l0 + r) * 128 + 64 + d;
                #pragma unroll
                for (int hh2 = 0; hh2 < 4; hh2++) Qe[base + hh2 * (LL * 128)] = v;
            }
        } else {
            for (int r = 0; r < 32; r++) {
                unsigned short v = f2b(acc[r] * Sk);
                int col = 64 + (d ^ ((r & 7) << 3));   // Ke swizzle (row&7 == r&7)
                int base = ((b * NH) * LL + l0 + r) * 128 + col;
                #pragma unroll
                for (int hh2 = 0; hh2 < 4; hh2++) Ke[base + hh2 * (LL * 128)] = v;
            }
        }
    }
    __syncthreads();
    // fused head projections: thread = output column c (q,k,v simultaneously)
    int c = t, hh = c >> 6, d = c & 63;
    float aq_[32], ak_[32], av_[32];
    #pragma unroll
    for (int r = 0; r < 32; r++) { aq_[r] = 0.f; ak_[r] = 0.f; av_[r] = 0.f; }
    for (int j = 0; j < 64; j += 4) {
        float q0w = wq[(j + 0) * 256 + c], q1w = wq[(j + 1) * 256 + c];
        float q2w = wq[(j + 2) * 256 + c], q3w = wq[(j + 3) * 256 + c];
        float k0w = wk[(j + 0) * 256 + c], k1w = wk[(j + 1) * 256 + c];
        float k2w = wk[(j + 2) * 256 + c], k3w = wk[(j + 3) * 256 + c];
        float v0w = wv[(j + 0) * 256 + c], v1w = wv[(j + 1) * 256 + c];
        float v2w = wv[(j + 2) * 256 + c], v3w = wv[(j + 3) * 256 + c];
        #pragma unroll
        for (int r = 0; r < 32; r++) {
            float4 xv = *(const float4*)&lx[r][j];
            aq_[r] += xv.x * q0w + xv.y * q1w + xv.z * q2w + xv.w * q3w;
            ak_[r] += xv.x * k0w + xv.y * k1w + xv.z * k2w + xv.w * k3w;
            av_[r] += xv.x * v0w + xv.y * v1w + xv.z * v2w + xv.w * v3w;
        }
    }
    int outbase = (b * NH + hh) * LL + l0;
    #pragma unroll
    for (int r = 0; r < 32; r++) Qe[(outbase + r) * 128 + d] = f2b(aq_[r] * 0.125f);
    #pragma unroll
    for (int r = 0; r < 32; r++)
        Ke[(outbase + r) * 128 + (d ^ ((r & 7) << 3))] = f2b(ak_[r]);
    // VeT with swizzle: 8-element blocks permuted inside each 64-col block
    long vbase = ((long)(b * NH + hh) * 64 + d) * LL;
    int lblk = l0 & ~63, loff = l0 & 63;
    #pragma unroll
    for (int rb = 0; rb < 4; rb++) {
        u16x8 vv;
        #pragma unroll
        for (int k = 0; k < 8; k++) {
            int r = rb * 8 + k;
            vv[k] = f2b(av_[r] + luv[r][d]);
        }
        int off = (loff + rb * 8) ^ ((d & 7) << 3);
        *(u16x8*)&VeT[vbase + lblk + off] = vv;
    }
}

// ---------- K3: attention core (two-pass, swapped-QK layout, async dbuf LDS) ----------
// grid (32 qtiles, 4 heads, 8 batches), 256 threads = 4 waves; wave w owns q-rows
// w*16..w*16+15. QK MFMA computed SWAPPED (mfma(kb, aq)) so each lane holds 4
// consecutive k-cols of one q-row (q=l15): attn stores are float4 NONTEMPORAL
// (bypass L2 -- the 537MB stream must not evict the cache-resident Ke/VeT).
__global__ __launch_bounds__(256) void k_attn(const ushort_t* __restrict__ Qe,
                                              const ushort_t* __restrict__ Ke,
                                              const ushort_t* __restrict__ VeT,
                                              const unsigned int* __restrict__ mwords,
                                              float* __restrict__ ctx,
                                              float* __restrict__ attn) {
    // bijective XCD swizzle over 1024 blocks: lin%8 (XCD) picks the batch
    int lin = blockIdx.x + 32 * blockIdx.y + 128 * blockIdx.z;
    int sw  = ((lin & 7) << 7) | (lin >> 3);
    int qt = sw & 31, h = (sw >> 5) & 3, b = sw >> 7;

    int t = threadIdx.x, w = t >> 6, lane = t & 63, quad = lane >> 4, l15 = lane & 15;
    int q0 = qt * 64;
    int bh = b * NH + h;
    const ushort_t* QeB = Qe + (long)bh * LL * 128;
    const ushort_t* KeB = Ke + (long)bh * LL * 128;
    const ushort_t* VtB = VeT + (long)bh * 64 * LL;
    float* attnB = attn + (long)bh * LL * LL;
    const unsigned int* mB = mwords + (long)(b * LL) * 64;

    __shared__ ushort_t sKe[2][64 * 128];     // 32 KB dbuf (linear, swizzled content)
    __shared__ ushort_t sVT[2][64 * 64];      // 16 KB dbuf
    __shared__ unsigned int smask[64][66];    // 16.9 KB
    __shared__ ushort_t sPb[4][16][72];       //  9.2 KB per-wave unnormalized P (bf16)

    // stage this q-tile's mask bits (64 rows x 64 words) -- once
    #pragma unroll
    for (int i = 0; i < 16; i++) {
        int id = t + i * 256;
        smask[id >> 6][id & 63] = mB[(q0 + (id >> 6)) * 64 + (id & 63)];
    }

    // Q fragments for this wave's 16 rows (Qe linear); lane l15 = q-row
    bf16x8 aq[4];
    int qrow = q0 + w * 16 + l15;
    #pragma unroll
    for (int c = 0; c < 4; c++)
        aq[c] = *(const bf16x8*)&QeB[qrow * 128 + c * 32 + quad * 8];

    int swz = (l15 & 7) << 3;                  // element XOR for swizzled LDS reads
    float lsum = 0.f;                          // partial row sum for q-row l15

    // ---- pass A: row sums ----
    #pragma unroll
    for (int i = 0; i < 4; i++) {              // prologue: Ke tile 0 -> buf0
        int off = (t + i * 256) * 16;
        cp16((const char*)KeB + off, (char*)&sKe[0][0] + off);
    }
    for (int kt = 0; kt < 32; kt++) {
        int cur = kt & 1;
        __syncthreads();                       // tile kt resident; smask visible (kt=0)
        if (kt < 31) {
            size_t gb = (size_t)(kt + 1) * 64 * 256;
            #pragma unroll
            for (int i = 0; i < 4; i++) {
                int off = (t + i * 256) * 16;
                cp16((const char*)KeB + gb + off, (char*)&sKe[cur ^ 1][0] + off);
            }
        }
        #pragma unroll
        for (int nb = 0; nb < 4; nb++) {
            f32x4 s = (f32x4){0.f, 0.f, 0.f, 0.f};
            #pragma unroll
            for (int c = 0; c < 4; c++) {
                bf16x8 kb = *(const bf16x8*)&sKe[cur][(nb * 16 + l15) * 128 + ((c * 32 + quad * 8) ^ swz)];
                s = __builtin_amdgcn_mfma_f32_16x16x32_bf16(kb, aq[c], s, 0, 0, 0);
            }
            unsigned int word = smask[w * 16 + l15][kt * 2 + (nb >> 1)];
            #pragma unroll
            for (int reg = 0; reg < 4; reg++) {
                unsigned int bit = (word >> ((nb & 1) * 16 + quad * 4 + reg)) & 1u;
                lsum += bit ? 0.f : __expf(fminf(s[reg], 60.f));
            }
        }
    }
    // full row sum for q-row l15: reduce across the 4 quads
    {
        lsum += __shfl_xor(lsum, 16, 64);
        lsum += __shfl_xor(lsum, 32, 64);
    }
    float inv = (lsum > 0.f) ? 1.f / lsum : 0.f;   // inverse for row l15
    float invC[4];                                 // inverse for row quad*4+reg (ctx)
    #pragma unroll
    for (int reg = 0; reg < 4; reg++) invC[reg] = __shfl(inv, quad * 4 + reg, 16);

    // ---- pass B: normalized attn store + PV ----
    f32x4 cacc[4];
    #pragma unroll
    for (int db = 0; db < 4; db++) cacc[db] = (f32x4){0.f, 0.f, 0.f, 0.f};

    // prologue: tile 0 of Ke + VeT (buf0 free: all waves past pass-A kt=31 barrier)
    #pragma unroll
    for (int i = 0; i < 4; i++) {
        int off = (t + i * 256) * 16;
        cp16((const char*)KeB + off, (char*)&sKe[0][0] + off);
    }
    #pragma unroll
    for (int i = 0; i < 2; i++) {
        int off = (t + i * 256) * 16;          // LDS byte offset in 8 KB tile
        int d = off >> 7, cb = off & 127;      // row d (0..63), col byte
        cp16((const char*)VtB + (size_t)d * (LL * 2) + cb, (char*)&sVT[0][0] + off);
    }
    for (int kt = 0; kt < 32; kt++) {
        int cur = kt & 1;
        int k0 = kt * 64;
        __syncthreads();
        if (kt < 31) {
            size_t gKe = (size_t)(k0 + 64) * 256;
            #pragma unroll
            for (int i = 0; i < 4; i++) {
                int off = (t + i * 256) * 16;
                cp16((const char*)KeB + gKe + off, (char*)&sKe[cur ^ 1][0] + off);
            }
            #pragma unroll
            for (int i = 0; i < 2; i++) {
                int off = (t + i * 256) * 16;
                int d = off >> 7, cb = off & 127;
                cp16((const char*)VtB + (size_t)d * (LL * 2) + (size_t)(k0 + 64) * 2 + cb,
                     (char*)&sVT[cur ^ 1][0] + off);
            }
        }
        #pragma unroll
        for (int nb = 0; nb < 4; nb++) {
            f32x4 s = (f32x4){0.f, 0.f, 0.f, 0.f};
            #pragma unroll
            for (int c = 0; c < 4; c++) {
                bf16x8 kb = *(const bf16x8*)&sKe[cur][(nb * 16 + l15) * 128 + ((c * 32 + quad * 8) ^ swz)];
                s = __builtin_amdgcn_mfma_f32_16x16x32_bf16(kb, aq[c], s, 0, 0, 0);
            }
            unsigned int word = smask[w * 16 + l15][kt * 2 + (nb >> 1)];
            u16x4 pk;
            f32x4 st;
            #pragma unroll
            for (int reg = 0; reg < 4; reg++) {
                unsigned int bit = (word >> ((nb & 1) * 16 + quad * 4 + reg)) & 1u;
                float p = bit ? 0.f : __expf(fminf(s[reg], 60.f));
                pk[reg] = f2b(p);
                st[reg] = p * inv;
            }
            *(u16x4*)&sPb[w][l15][nb * 16 + quad * 4] = pk;
            // nontemporal: 537MB write-once stream must bypass L2 (keeps Ke/VeT hot);
            // each instruction still writes 64B contiguous per row (HBM granule)
            __builtin_nontemporal_store(st,
                (f32x4*)&attnB[(long)(q0 + w * 16 + l15) * LL + k0 + nb * 16 + quad * 4]);
        }
        // ctx += P @ Ve (unnormalized P; normalized at the end)
        #pragma unroll
        for (int db = 0; db < 4; db++) {
            #pragma unroll
            for (int c2 = 0; c2 < 2; c2++) {
                bf16x8 a  = *(const bf16x8*)&sPb[w][l15][c2 * 32 + quad * 8];
                bf16x8 bb = *(const bf16x8*)&sVT[cur][(db * 16 + l15) * 64 + ((c2 * 32 + quad * 8) ^ swz)];
                cacc[db] = __builtin_amdgcn_mfma_f32_16x16x32_bf16(a, bb, cacc[db], 0, 0, 0);
            }
        }
    }
    // normalized ctx -> ws [b,L,256] fp32 (cacc row = quad*4+reg -> invC)
    #pragma unroll
    for (int db = 0; db < 4; db++)
        #pragma unroll
        for (int reg = 0; reg < 4; reg++) {
            int qr = q0 + w * 16 + quad * 4 + reg;
            ctx[((long)(b * LL) + qr) * 256 + h * 64 + db * 16 + l15] = cacc[db][reg] * invC[reg];
        }
}

// ---------- K5: fc + residual + LN1 + FFN + LN2 ----------
__global__ __launch_bounds__(256) void k_epi(const float* __restrict__ ctx,
                                             const float* __restrict__ x,
                                             const float* __restrict__ fcw,
                                             const float* __restrict__ g1,
                                             const float* __restrict__ b1,
                                             const float* __restrict__ f1,
                                             const float* __restrict__ f2,
                                             const float* __restrict__ g2,
                                             const float* __restrict__ b2w,
                                             float* __restrict__ res) {
    int w = threadIdx.x >> 6, lane = threadIdx.x & 63;
    int row = blockIdx.x * 4 + w;
    const float* cr = ctx + (long)row * 256;
    float creg[4];
    #pragma unroll
    for (int i = 0; i < 4; i++) creg[i] = cr[i * 64 + lane];
    float acc = 0.f;
    #pragma unroll
    for (int j = 0; j < 256; j++) {
        float cj = __shfl(creg[j >> 6], j & 63, 64);
        acc += cj * fcw[j * 64 + lane];
    }
    float val = acc + x[row * 64 + lane];
    float mu = val;
    #pragma unroll
    for (int m = 1; m < 64; m <<= 1) mu += __shfl_xor(mu, m, 64);
    mu *= (1.f / 64.f);
    float d0 = val - mu;
    float var = d0 * d0;
    #pragma unroll
    for (int m = 1; m < 64; m <<= 1) var += __shfl_xor(var, m, 64);
    var *= (1.f / 64.f);
    float enc = d0 * rsqrtf(var + 1e-5f) * g1[lane] + b1[lane];
    float a1 = 0.f;
    #pragma unroll
    for (int j = 0; j < 64; j++) a1 += __shfl(enc, j, 64) * f1[j * 64 + lane];
    float hrel = fmaxf(a1, 0.f);
    float a2 = 0.f;
    #pragma unroll
    for (int j = 0; j < 64; j++) a2 += __shfl(hrel, j, 64) * f2[j * 64 + lane];
    float v2 = a2 + enc;
    float mu2 = v2;
    #pragma unroll
    for (int m = 1; m < 64; m <<= 1) mu2 += __shfl_xor(mu2, m, 64);
    mu2 *= (1.f / 64.f);
    float d2 = v2 - mu2;
    float var2 = d2 * d2;
    #pragma unroll
    for (int m = 1; m < 64; m <<= 1) var2 += __shfl_xor(var2, m, 64);
    var2 *= (1.f / 64.f);
    float outv = d2 * rsqrtf(var2 + 1e-5f) * g2[lane] + b2w[lane];
    res[row * 64 + lane] = outv;
}

// ---------- launch ----------
extern "C" void kernel_launch(void* const* d_in, const int* in_sizes, int n_in,
                              void* d_out, int out_size, void* d_ws, size_t ws_size,
                              hipStream_t stream) {
    const float* x    = (const float*)d_in[0];
    const int*   mask = (const int*)d_in[1];
    const float* u    = (const float*)d_in[2];
    const float* wq   = (const float*)d_in[3];
    const float* wk   = (const float*)d_in[4];
    const float* wv   = (const float*)d_in[5];
    const float* uqw  = (const float*)d_in[6];
    const float* ukw  = (const float*)d_in[7];
    const float* uvw  = (const float*)d_in[8];
    const float* sq1  = (const float*)d_in[9];
    const float* sq2  = (const float*)d_in[10];
    const float* sk1  = (const float*)d_in[11];
    const float* sk2  = (const float*)d_in[12];
    const float* sv1  = (const float*)d_in[13];
    const float* sv2  = (const float*)d_in[14];
    const float* fcw  = (const float*)d_in[15];
    const float* g1   = (const float*)d_in[16];
    const float* b1   = (const float*)d_in[17];
    const float* f1   = (const float*)d_in[18];
    const float* f2   = (const float*)d_in[19];
    const float* g2   = (const float*)d_in[20];
    const float* b2w  = (const float*)d_in[21];

    char* ws = (char*)d_ws;
    float*        gates  = (float*)(ws + 0);
    unsigned int* mwords = (unsigned int*)(ws + 4096);              // 4,194,304 B
    ushort_t*     Qe     = (ushort_t*)(ws + 4198400);               // 16,777,216 B
    ushort_t*     Ke     = (ushort_t*)(ws + 20975616);              // 16,777,216 B
    ushort_t*     VeT    = (ushort_t*)(ws + 37752832);              //  8,388,608 B
    float*        ctx    = (float*)(ws + 46141440);                 // 16,777,216 B (end ~63 MB)

    float* res  = (float*)d_out;
    float* attn = (float*)d_out + (size_t)BB * LL * DM;             // offset 1,048,576 elems

    k_maskpack<<<dim3(4096), dim3(256), 0, stream>>>(mask, mwords);
    k_gates<<<dim3(8, 3), dim3(64), 0, stream>>>(u, sq1, sq2, sk1, sk2, sv1, sv2, gates);
    k_proj<<<dim3(64, 8), dim3(256), 0, stream>>>(x, wq, wk, wv, uqw, ukw, uvw, gates, Qe, Ke, VeT);
    k_attn<<<dim3(32, 4, 8), dim3(256), 0, stream>>>(Qe, Ke, VeT, mwords, ctx, attn);
    k_epi<<<dim3(4096), dim3(256), 0, stream>>>(ctx, x, fcw, g1, b1, f1, f2, g2, b2w, res);
}

// Round 6
// 996.659 us; speedup vs baseline: 1.1121x; 1.0228x over previous
//
#include <hip/hip_runtime.h>
#include <hip/hip_bf16.h>
#include <stdint.h>

// ---------- types ----------
typedef __bf16  bf16x8  __attribute__((ext_vector_type(8)));
typedef float   f32x4   __attribute__((ext_vector_type(4)));
typedef unsigned short u16x8 __attribute__((ext_vector_type(8)));
typedef unsigned short u16x4 __attribute__((ext_vector_type(4)));
typedef unsigned short ushort_t;

__device__ __forceinline__ unsigned short f2b(float f) {
    __hip_bfloat16 h = __float2bfloat16(f);   // RNE
    return *reinterpret_cast<unsigned short*>(&h);
}

// async 16B global->LDS (direct-to-LDS DMA; LDS dest is wave-uniform base + lane*16)
__device__ __forceinline__ void cp16(const void* g, void* l) {
    __builtin_amdgcn_global_load_lds(
        (const __attribute__((address_space(1))) unsigned int*)g,
        (__attribute__((address_space(3))) unsigned int*)l,
        16, 0, 0);
}

// dims
#define BB 8
#define LL 2048
#define DM 64
#define NH 4
#define DK 64

// ---------- K0: pack mask int32 -> bits (k-major, 32 keys/word) ----------
__global__ __launch_bounds__(256) void k_maskpack(const int* __restrict__ mask,
                                                  unsigned int* __restrict__ words) {
    int tid = blockIdx.x * 256 + threadIdx.x;        // word index, 1,048,576 total
    const int4* p = reinterpret_cast<const int4*>(mask) + (size_t)tid * 8;
    unsigned int wbits = 0u;
    #pragma unroll
    for (int i = 0; i < 8; i++) {
        int4 v = p[i];
        wbits |= (v.x != 0 ? 1u << (4 * i + 0) : 0u);
        wbits |= (v.y != 0 ? 1u << (4 * i + 1) : 0u);
        wbits |= (v.z != 0 ? 1u << (4 * i + 2) : 0u);
        wbits |= (v.w != 0 ? 1u << (4 * i + 3) : 0u);
    }
    words[tid] = wbits;
}

// ---------- K1: gates S_q,S_k,S_v per batch ----------
__global__ __launch_bounds__(64) void k_gates(const float* __restrict__ u,
                                              const float* s1q, const float* s2q,
                                              const float* s1k, const float* s2k,
                                              const float* s1v, const float* s2v,
                                              float* __restrict__ gates) {
    int b = blockIdx.x, g = blockIdx.y, lane = threadIdx.x;
    const float* s1 = (g == 0) ? s1q : (g == 1) ? s1k : s1v;
    const float* s2 = (g == 0) ? s2q : (g == 1) ? s2k : s2v;
    float ur = u[b * 64 + lane];
    float acc = 0.f;
    for (int j = 0; j < 64; j++) {
        float uj = __shfl(ur, j, 64);
        if (lane < 32) acc += uj * s1[j * 32 + lane];
    }
    float r = (lane < 32) ? fmaxf(acc, 0.f) * s2[lane] : 0.f;
    for (int m = 32; m >= 1; m >>= 1) r += __shfl_xor(r, m, 64);
    if (lane == 0) gates[b * 3 + g] = r;
}

// ---------- K2: projections ----------
// Qe [b,h,L,128] linear (scaled 1/8).
// Ke [b,h,L,128] with col XOR-swizzle: element (l,c) stored at c ^ ((l&7)<<3).
// VeT [b,h,64,L] = (V+uV)^T with per-64-block col swizzle: within each 64-col block,
//   element (d,l) stored at (l&63) ^ ((d&7)<<3).
__global__ __launch_bounds__(256) void k_proj(const float* __restrict__ x,
                                              const float* __restrict__ wq,
                                              const float* __restrict__ wk,
                                              const float* __restrict__ wv,
                                              const float* __restrict__ uqw,
                                              const float* __restrict__ ukw,
                                              const float* __restrict__ uvw,
                                              const float* __restrict__ gates,
                                              ushort_t* __restrict__ Qe,
                                              ushort_t* __restrict__ Ke,
                                              ushort_t* __restrict__ VeT) {
    int lt = blockIdx.x, b = blockIdx.y, t = threadIdx.x;
    int l0 = lt * 32;
    __shared__ float lx[32][68];
    __shared__ float luv[32][68];
    #pragma unroll
    for (int i = 0; i < 2; i++) {      // stage x tile: 32x64 floats
        int id = t + i * 256;
        int r = id >> 4, c4 = id & 15;
        float4 v = *(const float4*)&x[((b * LL) + l0 + r) * 64 + c4 * 4];
        *(float4*)&lx[r][c4 * 4] = v;
    }
    __syncthreads();
    float Sq = gates[b * 3 + 0], Sk = gates[b * 3 + 1], Sv = gates[b * 3 + 2];
    // u-projections (waves 0..2)
    if (t < 192) {
        int m = t >> 6, d = t & 63;
        const float* uw = (m == 0) ? uqw : (m == 1) ? ukw : uvw;
        float acc[32];
        #pragma unroll
        for (int r = 0; r < 32; r++) acc[r] = 0.f;
        for (int j = 0; j < 64; j += 4) {
            float w0 = uw[(j + 0) * 64 + d], w1 = uw[(j + 1) * 64 + d];
            float w2 = uw[(j + 2) * 64 + d], w3 = uw[(j + 3) * 64 + d];
            #pragma unroll
            for (int r = 0; r < 32; r++) {
                float4 xv = *(const float4*)&lx[r][j];
                acc[r] += xv.x * w0 + xv.y * w1 + xv.z * w2 + xv.w * w3;
            }
        }
        if (m == 2) {
            #pragma unroll
            for (int r = 0; r < 32; r++) luv[r][d] = acc[r] * Sv;
        } else if (m == 0) {
            for (int r = 0; r < 32; r++) {
                unsigned short v = f2b(acc[r] * Sq * 0.125f);
                int base = ((b * NH) * LL + l0 + r) * 128 + 64 + d;
                #pragma unroll
                for (int hh2 = 0; hh2 < 4; hh2++) Qe[base + hh2 * (LL * 128)] = v;
            }
        } else {
            for (int r = 0; r < 32; r++) {
                unsigned short v = f2b(acc[r] * Sk);
                int col = 64 + (d ^ ((r & 7) << 3));   // Ke swizzle (row&7 == r&7)
                int base = ((b * NH) * LL + l0 + r) * 128 + col;
                #pragma unroll
                for (int hh2 = 0; hh2 < 4; hh2++) Ke[base + hh2 * (LL * 128)] = v;
            }
        }
    }
    __syncthreads();
    // fused head projections: thread = output column c (q,k,v simultaneously)
    int c = t, hh = c >> 6, d = c & 63;
    float aq_[32], ak_[32], av_[32];
    #pragma unroll
    for (int r = 0; r < 32; r++) { aq_[r] = 0.f; ak_[r] = 0.f; av_[r] = 0.f; }
    for (int j = 0; j < 64; j += 4) {
        float q0w = wq[(j + 0) * 256 + c], q1w = wq[(j + 1) * 256 + c];
        float q2w = wq[(j + 2) * 256 + c], q3w = wq[(j + 3) * 256 + c];
        float k0w = wk[(j + 0) * 256 + c], k1w = wk[(j + 1) * 256 + c];
        float k2w = wk[(j + 2) * 256 + c], k3w = wk[(j + 3) * 256 + c];
        float v0w = wv[(j + 0) * 256 + c], v1w = wv[(j + 1) * 256 + c];
        float v2w = wv[(j + 2) * 256 + c], v3w = wv[(j + 3) * 256 + c];
        #pragma unroll
        for (int r = 0; r < 32; r++) {
            float4 xv = *(const float4*)&lx[r][j];
            aq_[r] += xv.x * q0w + xv.y * q1w + xv.z * q2w + xv.w * q3w;
            ak_[r] += xv.x * k0w + xv.y * k1w + xv.z * k2w + xv.w * k3w;
            av_[r] += xv.x * v0w + xv.y * v1w + xv.z * v2w + xv.w * v3w;
        }
    }
    int outbase = (b * NH + hh) * LL + l0;
    #pragma unroll
    for (int r = 0; r < 32; r++) Qe[(outbase + r) * 128 + d] = f2b(aq_[r] * 0.125f);
    #pragma unroll
    for (int r = 0; r < 32; r++)
        Ke[(outbase + r) * 128 + (d ^ ((r & 7) << 3))] = f2b(ak_[r]);
    // VeT with swizzle: 8-element blocks permuted inside each 64-col block
    long vbase = ((long)(b * NH + hh) * 64 + d) * LL;
    int lblk = l0 & ~63, loff = l0 & 63;
    #pragma unroll
    for (int rb = 0; rb < 4; rb++) {
        u16x8 vv;
        #pragma unroll
        for (int k = 0; k < 8; k++) {
            int r = rb * 8 + k;
            vv[k] = f2b(av_[r] + luv[r][d]);
        }
        int off = (loff + rb * 8) ^ ((d & 7) << 3);
        *(u16x8*)&VeT[vbase + lblk + off] = vv;
    }
}

// ---------- K3: attention core (two-pass, swapped-QK, full-line NT stores) ----------
// grid (32 qtiles, 4 heads, 8 batches), 256 threads = 4 waves; wave w owns q-rows
// w*16..w*16+15. Swapped QK MFMA: lane holds 4 k-cols of q-row l15. Normalized P
// is round-tripped through a per-wave LDS tile (sSt) so each NT store instruction
// covers 8 rows x 128B FULL lines (NT partial-line writes were the ~230us pin).
// Mask bits staged per-2-tiles into a tiny LDS dbuf (replaces the 17KB smask).
__global__ __launch_bounds__(256) void k_attn(const ushort_t* __restrict__ Qe,
                                              const ushort_t* __restrict__ Ke,
                                              const ushort_t* __restrict__ VeT,
                                              const unsigned int* __restrict__ mwords,
                                              float* __restrict__ ctx,
                                              float* __restrict__ attn) {
    // bijective XCD swizzle over 1024 blocks: lin%8 (XCD) picks the batch
    int lin = blockIdx.x + 32 * blockIdx.y + 128 * blockIdx.z;
    int sw  = ((lin & 7) << 7) | (lin >> 3);
    int qt = sw & 31, h = (sw >> 5) & 3, b = sw >> 7;

    int t = threadIdx.x, w = t >> 6, lane = t & 63, quad = lane >> 4, l15 = lane & 15;
    int q0 = qt * 64;
    int bh = b * NH + h;
    const ushort_t* QeB = Qe + (long)bh * LL * 128;
    const ushort_t* KeB = Ke + (long)bh * LL * 128;
    const ushort_t* VtB = VeT + (long)bh * 64 * LL;
    float* attnB = attn + (long)bh * LL * LL;
    const unsigned int* mB = mwords + (long)(b * LL) * 64;

    __shared__ ushort_t sKe[2][64 * 128];     // 32 KB dbuf (linear, swizzled content)
    __shared__ ushort_t sVT[2][64 * 64];      // 16 KB dbuf
    __shared__ ushort_t sPb[4][16][72];       //  9 KB per-wave unnormalized P (bf16)
    __shared__ float    sSt[4][16][68];       // 17 KB per-wave normalized P (f32)
    __shared__ unsigned int msk[2][64][4];    //  2 KB mask dbuf (2 tiles per buf)

    // Q fragments for this wave's 16 rows (Qe linear); lane l15 = q-row
    bf16x8 aq[4];
    int qrow = q0 + w * 16 + l15;
    #pragma unroll
    for (int c = 0; c < 4; c++)
        aq[c] = *(const bf16x8*)&QeB[qrow * 128 + c * 32 + quad * 8];

    int swz = (l15 & 7) << 3;                  // element XOR for swizzled LDS reads
    float lsum = 0.f;                          // partial row sum for q-row l15
    int srow = lane >> 3, scol = lane & 7;     // full-line store mapping

    // ---- pass A: row sums ----
    #pragma unroll
    for (int i = 0; i < 4; i++) {              // prologue: Ke tile 0 -> buf0
        int off = (t + i * 256) * 16;
        cp16((const char*)KeB + off, (char*)&sKe[0][0] + off);
    }
    if (w == 0)                                // prologue: mask words tiles 0,1 -> buf0
        cp16((const char*)&mB[(q0 + lane) * 64], (char*)&msk[0][0][0] + lane * 16);
    for (int kt = 0; kt < 32; kt++) {
        int cur = kt & 1;
        __syncthreads();                       // tile kt (Ke + mask) resident
        if (kt < 31) {
            size_t gb = (size_t)(kt + 1) * 64 * 256;
            #pragma unroll
            for (int i = 0; i < 4; i++) {
                int off = (t + i * 256) * 16;
                cp16((const char*)KeB + gb + off, (char*)&sKe[cur ^ 1][0] + off);
            }
        }
        if ((kt & 1) == 0 && kt < 30 && w == 0)   // mask for tiles kt+2, kt+3
            cp16((const char*)&mB[(q0 + lane) * 64 + kt * 2 + 4],
                 (char*)&msk[((kt >> 1) & 1) ^ 1][0][0] + lane * 16);
        uint2 mw = *(const uint2*)&msk[(kt >> 1) & 1][w * 16 + l15][(kt & 1) * 2];
        #pragma unroll
        for (int nb = 0; nb < 4; nb++) {
            f32x4 s = (f32x4){0.f, 0.f, 0.f, 0.f};
            #pragma unroll
            for (int c = 0; c < 4; c++) {
                bf16x8 kb = *(const bf16x8*)&sKe[cur][(nb * 16 + l15) * 128 + ((c * 32 + quad * 8) ^ swz)];
                s = __builtin_amdgcn_mfma_f32_16x16x32_bf16(kb, aq[c], s, 0, 0, 0);
            }
            unsigned int word = (nb & 2) ? mw.y : mw.x;
            #pragma unroll
            for (int reg = 0; reg < 4; reg++) {
                unsigned int bit = (word >> ((nb & 1) * 16 + quad * 4 + reg)) & 1u;
                lsum += bit ? 0.f : __expf(fminf(s[reg], 60.f));
            }
        }
    }
    // full row sum for q-row l15: reduce across the 4 quads
    {
        lsum += __shfl_xor(lsum, 16, 64);
        lsum += __shfl_xor(lsum, 32, 64);
    }
    float inv = (lsum > 0.f) ? 1.f / lsum : 0.f;   // inverse for row l15
    float invC[4];                                 // inverse for row quad*4+reg (ctx)
    #pragma unroll
    for (int reg = 0; reg < 4; reg++) invC[reg] = __shfl(inv, quad * 4 + reg, 16);

    // ---- pass B: full-line attn store + PV ----
    f32x4 cacc[4];
    #pragma unroll
    for (int db = 0; db < 4; db++) cacc[db] = (f32x4){0.f, 0.f, 0.f, 0.f};

    // prologue: tile 0 of Ke + VeT + mask (buf0 free: all waves past pass-A kt=31 barrier)
    #pragma unroll
    for (int i = 0; i < 4; i++) {
        int off = (t + i * 256) * 16;
        cp16((const char*)KeB + off, (char*)&sKe[0][0] + off);
    }
    #pragma unroll
    for (int i = 0; i < 2; i++) {
        int off = (t + i * 256) * 16;          // LDS byte offset in 8 KB tile
        int d = off >> 7, cb = off & 127;      // row d (0..63), col byte
        cp16((const char*)VtB + (size_t)d * (LL * 2) + cb, (char*)&sVT[0][0] + off);
    }
    if (w == 0)
        cp16((const char*)&mB[(q0 + lane) * 64], (char*)&msk[0][0][0] + lane * 16);
    for (int kt = 0; kt < 32; kt++) {
        int cur = kt & 1;
        int k0 = kt * 64;
        __syncthreads();
        if (kt < 31) {
            size_t gKe = (size_t)(k0 + 64) * 256;
            #pragma unroll
            for (int i = 0; i < 4; i++) {
                int off = (t + i * 256) * 16;
                cp16((const char*)KeB + gKe + off, (char*)&sKe[cur ^ 1][0] + off);
            }
            #pragma unroll
            for (int i = 0; i < 2; i++) {
                int off = (t + i * 256) * 16;
                int d = off >> 7, cb = off & 127;
                cp16((const char*)VtB + (size_t)d * (LL * 2) + (size_t)(k0 + 64) * 2 + cb,
                     (char*)&sVT[cur ^ 1][0] + off);
            }
        }
        if ((kt & 1) == 0 && kt < 30 && w == 0)
            cp16((const char*)&mB[(q0 + lane) * 64 + kt * 2 + 4],
                 (char*)&msk[((kt >> 1) & 1) ^ 1][0][0] + lane * 16);
        uint2 mw = *(const uint2*)&msk[(kt >> 1) & 1][w * 16 + l15][(kt & 1) * 2];
        #pragma unroll
        for (int nb = 0; nb < 4; nb++) {
            f32x4 s = (f32x4){0.f, 0.f, 0.f, 0.f};
            #pragma unroll
            for (int c = 0; c < 4; c++) {
                bf16x8 kb = *(const bf16x8*)&sKe[cur][(nb * 16 + l15) * 128 + ((c * 32 + quad * 8) ^ swz)];
                s = __builtin_amdgcn_mfma_f32_16x16x32_bf16(kb, aq[c], s, 0, 0, 0);
            }
            unsigned int word = (nb & 2) ? mw.y : mw.x;
            u16x4 pk;
            f32x4 st;
            #pragma unroll
            for (int reg = 0; reg < 4; reg++) {
                unsigned int bit = (word >> ((nb & 1) * 16 + quad * 4 + reg)) & 1u;
                float p = bit ? 0.f : __expf(fminf(s[reg], 60.f));
                pk[reg] = f2b(p);
                st[reg] = p * inv;
            }
            *(u16x4*)&sPb[w][l15][nb * 16 + quad * 4] = pk;
            *(f32x4*)&sSt[w][l15][nb * 16 + quad * 4] = st;   // normalized f32
        }
        // full-line NT stores: lane -> row srow (8 rows/instr), 16B at col scol*4;
        // 8 consecutive lanes cover one 128B line -> no partial-line penalty, no L2
        #pragma unroll
        for (int jr = 0; jr < 2; jr++)
            #pragma unroll
            for (int jc = 0; jc < 2; jc++) {
                f32x4 v = *(const f32x4*)&sSt[w][8 * jr + srow][jc * 32 + scol * 4];
                __builtin_nontemporal_store(v,
                    (f32x4*)&attnB[(long)(q0 + w * 16 + 8 * jr + srow) * LL + k0 + jc * 32 + scol * 4]);
            }
        // ctx += P @ Ve (unnormalized P; normalized at the end)
        #pragma unroll
        for (int db = 0; db < 4; db++) {
            #pragma unroll
            for (int c2 = 0; c2 < 2; c2++) {
                bf16x8 a  = *(const bf16x8*)&sPb[w][l15][c2 * 32 + quad * 8];
                bf16x8 bb = *(const bf16x8*)&sVT[cur][(db * 16 + l15) * 64 + ((c2 * 32 + quad * 8) ^ swz)];
                cacc[db] = __builtin_amdgcn_mfma_f32_16x16x32_bf16(a, bb, cacc[db], 0, 0, 0);
            }
        }
    }
    // normalized ctx -> ws [b,L,256] fp32 (cacc row = quad*4+reg -> invC)
    #pragma unroll
    for (int db = 0; db < 4; db++)
        #pragma unroll
        for (int reg = 0; reg < 4; reg++) {
            int qr = q0 + w * 16 + quad * 4 + reg;
            ctx[((long)(b * LL) + qr) * 256 + h * 64 + db * 16 + l15] = cacc[db][reg] * invC[reg];
        }
}

// ---------- K5: fc + residual + LN1 + FFN + LN2 ----------
__global__ __launch_bounds__(256) void k_epi(const float* __restrict__ ctx,
                                             const float* __restrict__ x,
                                             const float* __restrict__ fcw,
                                             const float* __restrict__ g1,
                                             const float* __restrict__ b1,
                                             const float* __restrict__ f1,
                                             const float* __restrict__ f2,
                                             const float* __restrict__ g2,
                                             const float* __restrict__ b2w,
                                             float* __restrict__ res) {
    int w = threadIdx.x >> 6, lane = threadIdx.x & 63;
    int row = blockIdx.x * 4 + w;
    const float* cr = ctx + (long)row * 256;
    float creg[4];
    #pragma unroll
    for (int i = 0; i < 4; i++) creg[i] = cr[i * 64 + lane];
    float acc = 0.f;
    #pragma unroll
    for (int j = 0; j < 256; j++) {
        float cj = __shfl(creg[j >> 6], j & 63, 64);
        acc += cj * fcw[j * 64 + lane];
    }
    float val = acc + x[row * 64 + lane];
    float mu = val;
    #pragma unroll
    for (int m = 1; m < 64; m <<= 1) mu += __shfl_xor(mu, m, 64);
    mu *= (1.f / 64.f);
    float d0 = val - mu;
    float var = d0 * d0;
    #pragma unroll
    for (int m = 1; m < 64; m <<= 1) var += __shfl_xor(var, m, 64);
    var *= (1.f / 64.f);
    float enc = d0 * rsqrtf(var + 1e-5f) * g1[lane] + b1[lane];
    float a1 = 0.f;
    #pragma unroll
    for (int j = 0; j < 64; j++) a1 += __shfl(enc, j, 64) * f1[j * 64 + lane];
    float hrel = fmaxf(a1, 0.f);
    float a2 = 0.f;
    #pragma unroll
    for (int j = 0; j < 64; j++) a2 += __shfl(hrel, j, 64) * f2[j * 64 + lane];
    float v2 = a2 + enc;
    float mu2 = v2;
    #pragma unroll
    for (int m = 1; m < 64; m <<= 1) mu2 += __shfl_xor(mu2, m, 64);
    mu2 *= (1.f / 64.f);
    float d2 = v2 - mu2;
    float var2 = d2 * d2;
    #pragma unroll
    for (int m = 1; m < 64; m <<= 1) var2 += __shfl_xor(var2, m, 64);
    var2 *= (1.f / 64.f);
    float outv = d2 * rsqrtf(var2 + 1e-5f) * g2[lane] + b2w[lane];
    res[row * 64 + lane] = outv;
}

// ---------- launch ----------
extern "C" void kernel_launch(void* const* d_in, const int* in_sizes, int n_in,
                              void* d_out, int out_size, void* d_ws, size_t ws_size,
                              hipStream_t stream) {
    const float* x    = (const float*)d_in[0];
    const int*   mask = (const int*)d_in[1];
    const float* u    = (const float*)d_in[2];
    const float* wq   = (const float*)d_in[3];
    const float* wk   = (const float*)d_in[4];
    const float* wv   = (const float*)d_in[5];
    const float* uqw  = (const float*)d_in[6];
    const float* ukw  = (const float*)d_in[7];
    const float* uvw  = (const float*)d_in[8];
    const float* sq1  = (const float*)d_in[9];
    const float* sq2  = (const float*)d_in[10];
    const float* sk1  = (const float*)d_in[11];
    const float* sk2  = (const float*)d_in[12];
    const float* sv1  = (const float*)d_in[13];
    const float* sv2  = (const float*)d_in[14];
    const float* fcw  = (const float*)d_in[15];
    const float* g1   = (const float*)d_in[16];
    const float* b1   = (const float*)d_in[17];
    const float* f1   = (const float*)d_in[18];
    const float* f2   = (const float*)d_in[19];
    const float* g2   = (const float*)d_in[20];
    const float* b2w  = (const float*)d_in[21];

    char* ws = (char*)d_ws;
    float*        gates  = (float*)(ws + 0);
    unsigned int* mwords = (unsigned int*)(ws + 4096);              // 4,194,304 B
    ushort_t*     Qe     = (ushort_t*)(ws + 4198400);               // 16,777,216 B
    ushort_t*     Ke     = (ushort_t*)(ws + 20975616);              // 16,777,216 B
    ushort_t*     VeT    = (ushort_t*)(ws + 37752832);              //  8,388,608 B
    float*        ctx    = (float*)(ws + 46141440);                 // 16,777,216 B (end ~63 MB)

    float* res  = (float*)d_out;
    float* attn = (float*)d_out + (size_t)BB * LL * DM;             // offset 1,048,576 elems

    k_maskpack<<<dim3(4096), dim3(256), 0, stream>>>(mask, mwords);
    k_gates<<<dim3(8, 3), dim3(64), 0, stream>>>(u, sq1, sq2, sk1, sk2, sv1, sv2, gates);
    k_proj<<<dim3(64, 8), dim3(256), 0, stream>>>(x, wq, wk, wv, uqw, ukw, uvw, gates, Qe, Ke, VeT);
    k_attn<<<dim3(32, 4, 8), dim3(256), 0, stream>>>(Qe, Ke, VeT, mwords, ctx, attn);
    k_epi<<<dim3(4096), dim3(256), 0, stream>>>(ctx, x, fcw, g1, b1, f1, f2, g2, b2w, res);
}